// Round 1
// baseline (195.309 us; speedup 1.0000x reference)
//
#include <hip/hip_runtime.h>

// Problem constants (fixed by reference setup_inputs):
//   BATCH=16384, P=16 persons/group, D=2048  ->  G=1024 groups
// result = mean_g [ (1/120) * sum_{i<j} (1 - f_i . f_j) ]
//        = 1 - sum_{g,d} (s_{g,d}^2 - sq_{g,d}) / (240 * G)
// where s = column sum over the 16 rows, sq = column sum of squares.
#define DD 2048
#define PP 16
#define GG 1024
#define CPG (DD / 4)              // float4 chunks per row = 512
#define TOTAL_CHUNKS (GG * CPG)   // 524288 -> 2048 blocks x 256 threads

__global__ __launch_bounds__(256) void pairdist_reduce(
    const float* __restrict__ f, float* __restrict__ accum)
{
    const int idx = blockIdx.x * 256 + threadIdx.x;   // one (g, chunk) per thread
    const int g = idx >> 9;                           // idx / CPG
    const int c = idx & (CPG - 1);                    // idx % CPG

    const float4* base =
        reinterpret_cast<const float4*>(f) + (size_t)g * (PP * CPG) + c;

    float sx = 0.f, sy = 0.f, sz = 0.f, sw = 0.f, sq = 0.f;
#pragma unroll
    for (int i = 0; i < PP; ++i) {
        float4 v = base[i * CPG];                     // row stride = 8 KB, coalesced per wave
        sx += v.x; sy += v.y; sz += v.z; sw += v.w;
        sq += v.x * v.x + v.y * v.y + v.z * v.z + v.w * v.w;
    }
    // per-column (s^2 - sq): small magnitude, safe fp32 accumulation
    float acc = (sx * sx + sy * sy + sz * sz + sw * sw) - sq;

    // wave(64) shuffle reduction
#pragma unroll
    for (int off = 32; off > 0; off >>= 1)
        acc += __shfl_down(acc, off, 64);

    __shared__ float lds[4];
    const int lane = threadIdx.x & 63;
    const int wave = threadIdx.x >> 6;
    if (lane == 0) lds[wave] = acc;
    __syncthreads();
    if (threadIdx.x == 0) {
        float b = lds[0] + lds[1] + lds[2] + lds[3];
        atomicAdd(accum, b);   // 2048 atomics total, device scope (cross-XCD safe)
    }
}

__global__ void pairdist_finalize(const float* __restrict__ accum,
                                  float* __restrict__ out)
{
    out[0] = 1.0f - accum[0] * (1.0f / (240.0f * (float)GG));
}

extern "C" void kernel_launch(void* const* d_in, const int* in_sizes, int n_in,
                              void* d_out, int out_size, void* d_ws, size_t ws_size,
                              hipStream_t stream)
{
    const float* f = (const float*)d_in[0];
    float* out = (float*)d_out;
    // accumulator lives in workspace (re-poisoned each call -> must zero it)
    float* acc = (ws_size >= sizeof(float)) ? (float*)d_ws : out;

    hipMemsetAsync(acc, 0, sizeof(float), stream);
    pairdist_reduce<<<TOTAL_CHUNKS / 256, 256, 0, stream>>>(f, acc);
    pairdist_finalize<<<1, 1, 0, stream>>>(acc, out);
}

// Round 4
// 181.815 us; speedup vs baseline: 1.0742x; 1.0742x over previous
//
#include <hip/hip_runtime.h>

// BATCH=16384, P=16, D=2048 -> G=1024 groups.
// result = 1 - sum_{g,d} (s^2 - sq) / (240*G),  s/sq = column sum / sum-of-squares
// over the 16 rows of each group.
//
// Two-pass deterministic reduction: no memset, no atomics.
//   pass 1: 2048 blocks x 256 threads, one (group, float4-chunk) per thread,
//           block partial -> ws[blockIdx]
//   pass 2: 1 block x 256 threads reduces the 2048 partials, writes scalar.
#define DD 2048
#define PP 16
#define GG 1024
#define CPG (DD / 4)              // float4 chunks per row = 512
#define NBLK (GG * CPG / 256)     // 2048 partial blocks

// native clang vector type: __builtin_nontemporal_load requires it
// (HIP's float4 is a struct and is rejected)
typedef float v4f __attribute__((ext_vector_type(4)));

__global__ __launch_bounds__(256) void pairdist_partial(
    const float* __restrict__ f, float* __restrict__ part)
{
    const int idx = blockIdx.x * 256 + threadIdx.x;
    const int g = idx >> 9;                           // idx / CPG
    const int c = idx & (CPG - 1);                    // idx % CPG

    const v4f* base =
        reinterpret_cast<const v4f*>(f) + (size_t)g * (PP * CPG) + c;

    float sx = 0.f, sy = 0.f, sz = 0.f, sw = 0.f, sq = 0.f;
#pragma unroll
    for (int i = 0; i < PP; ++i) {
        // streamed exactly once -> nontemporal (nt) to skip L2 pollution
        v4f v = __builtin_nontemporal_load(base + i * CPG);
        sx += v.x; sy += v.y; sz += v.z; sw += v.w;
        sq += v.x * v.x + v.y * v.y + v.z * v.z + v.w * v.w;
    }
    float acc = (sx * sx + sy * sy + sz * sz + sw * sw) - sq;

    // wave(64) shuffle reduction, then 4 waves -> LDS -> block sum
#pragma unroll
    for (int off = 32; off > 0; off >>= 1)
        acc += __shfl_down(acc, off, 64);

    __shared__ float lds[4];
    const int lane = threadIdx.x & 63;
    const int wave = threadIdx.x >> 6;
    if (lane == 0) lds[wave] = acc;
    __syncthreads();
    if (threadIdx.x == 0)
        part[blockIdx.x] = lds[0] + lds[1] + lds[2] + lds[3];  // plain store, no init needed
}

__global__ __launch_bounds__(256) void pairdist_final(
    const float* __restrict__ part, float* __restrict__ out)
{
    float a = 0.f;
#pragma unroll
    for (int i = 0; i < NBLK / 256; ++i)              // 8 partials per thread
        a += part[threadIdx.x + i * 256];

#pragma unroll
    for (int off = 32; off > 0; off >>= 1)
        a += __shfl_down(a, off, 64);

    __shared__ float lds[4];
    const int lane = threadIdx.x & 63;
    const int wave = threadIdx.x >> 6;
    if (lane == 0) lds[wave] = a;
    __syncthreads();
    if (threadIdx.x == 0) {
        float t = lds[0] + lds[1] + lds[2] + lds[3];
        out[0] = 1.0f - t * (1.0f / (240.0f * (float)GG));
    }
}

extern "C" void kernel_launch(void* const* d_in, const int* in_sizes, int n_in,
                              void* d_out, int out_size, void* d_ws, size_t ws_size,
                              hipStream_t stream)
{
    const float* f = (const float*)d_in[0];
    float* part = (float*)d_ws;        // 2048 floats = 8 KB of the workspace
    float* out = (float*)d_out;

    pairdist_partial<<<NBLK, 256, 0, stream>>>(f, part);
    pairdist_final<<<1, 256, 0, stream>>>(part, out);
}